// Round 2
// baseline (352.649 us; speedup 1.0000x reference)
//
#include <hip/hip_runtime.h>
#include <hip/hip_bf16.h>

#define B_SZ 100000
#define NTOT 200000
#define NN   1000000
#define DIM  128

#define NB_INIT   3907              // ceil(1e6/256)
#define NB_WFRAG  32
#define NB_CLAIM  782               // ceil(2e5/256)
#define NB_COPY   2048
#define NB_MAIN   3125              // 200000 rows / 16 per wave / 4 waves

typedef short bf16x8 __attribute__((ext_vector_type(8)));
typedef float f32x4  __attribute__((ext_vector_type(4)));

__device__ __forceinline__ short f2bf(float f) {
    union { float f; unsigned u; } v; v.f = f;
    unsigned u = v.u;
    u += 0x7fffu + ((u >> 16) & 1u);
    return (short)(u >> 16);
}

// ---------------- launch 1: owner init  ||  weight packing ----------------
//  PA[k][n] = W_node[n][k] + (k==n)            (applied to prev)
//  PQ[k][n] = sum_m W_node[n][m]*W_nig[m][k]   (applied to nbr)
//  cvec[n]  = b_node[n] + sum_k b_nig[k]*W_node[n][k]
// B-fragment layout (16x16x32 bf16): frag (kc,nc), lane l holds
//   col n = nc*16 + (l&15), k = kc*32 + (l>>4)*8 + i, i=0..7
__global__ __launch_bounds__(256) void k_init_weights(
        int* __restrict__ owner,
        const float* __restrict__ Wnig, const float* __restrict__ bnig,
        const float* __restrict__ Wnode, const float* __restrict__ bnode,
        short* __restrict__ PA, short* __restrict__ PQ,
        float* __restrict__ cvec) {
    int b = blockIdx.x, t = threadIdx.x;
    if (b < NB_INIT) {
        int i = b * 256 + t;
        if (i < NN) owner[i] = -1;
    } else if (b < NB_INIT + NB_WFRAG) {
        int b2 = b - NB_INIT;              // fragment index kc*8+nc
        int lane = t & 63, ig = t >> 6;    // ig in 0..3 -> i = 2*ig, 2*ig+1
        int kc = b2 >> 3, nc = b2 & 7;
        int n = nc * 16 + (lane & 15);
        int kbase = kc * 32 + (lane >> 4) * 8;
        int fo = (b2 * 64 + lane) * 8;
        for (int ii = 0; ii < 2; ++ii) {
            int i = ig * 2 + ii;
            int k = kbase + i;
            float a = Wnode[n * DIM + k] + (k == n ? 1.0f : 0.0f);
            PA[fo + i] = f2bf(a);
            float q = 0.f;
            for (int m = 0; m < DIM; ++m) q += Wnode[n * DIM + m] * Wnig[m * DIM + k];
            PQ[fo + i] = f2bf(q);
        }
    } else {
        if (t < DIM) {
            float c = bnode[t];
            for (int k = 0; k < DIM; ++k) c += bnig[k] * Wnode[t * DIM + k];
            cvec[t] = c;
        }
    }
}

// ---------------- launch 2: ownership claim ----------------
// winner = max global code; src codes [0,B), dst codes [B,2B): dst beats src,
// later index beats earlier -> numpy sequential scatter semantics.
__global__ void k_claim(const int* __restrict__ src, const int* __restrict__ dst,
                        int* __restrict__ owner) {
    int i = blockIdx.x * 256 + threadIdx.x;
    if (i >= NTOT) return;
    int node = (i < B_SZ) ? src[i] : dst[i - B_SZ];
    atomicMax(&owner[node], i);
}

// ---------------- launch 3: fused copy + main ----------------
__global__ __launch_bounds__(256) void k_fused(
        const int* __restrict__ src, const int* __restrict__ dst,
        const float* __restrict__ prev,
        const float* __restrict__ nsrc, const float* __restrict__ ndst,
        const int* __restrict__ owner,
        const short* __restrict__ PA, const short* __restrict__ PQ,
        const float* __restrict__ cvec,
        float* __restrict__ out) {
    if (blockIdx.x < NB_COPY) {
        // ---- streaming copy of untouched rows: 32 lanes x float4 per row ----
        long t = (long)blockIdx.x * 256 + threadIdx.x;
        const long stride = (long)NB_COPY * 256;
        const long total = (long)NN * 32;
        for (; t < total; t += stride) {
            int row = (int)(t >> 5);
            if (owner[row] < 0) {
                int c = (int)(t & 31);
                float4 v = ((const float4*)prev)[(long)row * 32 + c];
                ((float4*)out)[(long)row * 32 + c] = v;
            }
        }
        return;
    }

    // ---- main: one wave per 16 batch rows ----
    int bid = blockIdx.x - NB_COPY;
    int wave = threadIdx.x >> 6;
    int lane = threadIdx.x & 63;
    int rowbase = (bid * 4 + wave) * 16;

    // A fragment: lane l -> row = l&15, k = kc*32 + (l>>4)*8 + i
    int arow = rowbase + (lane & 15);
    bool is_src = arow < B_SZ;
    int bi = is_src ? arow : arow - B_SZ;
    const int* ids = is_src ? src : dst;
    const float* nbr = is_src ? nsrc : ndst;
    int node_a = ids[bi];
    const float* prow = prev + (long)node_a * DIM;
    const float* nrow = nbr + (long)bi * DIM;
    int koff = (lane >> 4) * 8;

    f32x4 acc[8];
#pragma unroll
    for (int nc = 0; nc < 8; ++nc) acc[nc] = (f32x4){0.f, 0.f, 0.f, 0.f};

#pragma unroll
    for (int kc = 0; kc < 4; ++kc) {
        int k0 = kc * 32 + koff;
        float4 p0 = *(const float4*)(prow + k0);
        float4 p1 = *(const float4*)(prow + k0 + 4);
        float4 n0 = *(const float4*)(nrow + k0);
        float4 n1 = *(const float4*)(nrow + k0 + 4);
        bf16x8 aP, aN;
        aP[0] = f2bf(p0.x); aP[1] = f2bf(p0.y); aP[2] = f2bf(p0.z); aP[3] = f2bf(p0.w);
        aP[4] = f2bf(p1.x); aP[5] = f2bf(p1.y); aP[6] = f2bf(p1.z); aP[7] = f2bf(p1.w);
        aN[0] = f2bf(n0.x); aN[1] = f2bf(n0.y); aN[2] = f2bf(n0.z); aN[3] = f2bf(n0.w);
        aN[4] = f2bf(n1.x); aN[5] = f2bf(n1.y); aN[6] = f2bf(n1.z); aN[7] = f2bf(n1.w);
#pragma unroll
        for (int nc = 0; nc < 8; ++nc) {
            int fo = ((kc * 8 + nc) * 64 + lane) * 8;
            bf16x8 bA = *(const bf16x8*)(PA + fo);
            bf16x8 bQ = *(const bf16x8*)(PQ + fo);
            acc[nc] = __builtin_amdgcn_mfma_f32_16x16x32_bf16(aP, bA, acc[nc], 0, 0, 0);
            acc[nc] = __builtin_amdgcn_mfma_f32_16x16x32_bf16(aN, bQ, acc[nc], 0, 0, 0);
        }
    }

    // epilogue: write only winner rows
    // D fragment: lane l -> col = l&15 (in nc block), row = (l>>4)*4 + r
    int col0 = lane & 15;
    float cv[8];
#pragma unroll
    for (int nc = 0; nc < 8; ++nc) cv[nc] = cvec[nc * 16 + col0];

#pragma unroll
    for (int r = 0; r < 4; ++r) {
        int row = rowbase + (lane >> 4) * 4 + r;
        bool s = row < B_SZ;
        int b2 = s ? row : row - B_SZ;
        int node = (s ? src : dst)[b2];
        if (owner[node] == row) {
            float* orow = out + (long)node * DIM;
#pragma unroll
            for (int nc = 0; nc < 8; ++nc) {
                orow[nc * 16 + col0] = acc[nc][r] + cv[nc];
            }
        }
    }
}

extern "C" void kernel_launch(void* const* d_in, const int* in_sizes, int n_in,
                              void* d_out, int out_size, void* d_ws, size_t ws_size,
                              hipStream_t stream) {
    const int*   src  = (const int*)d_in[0];
    const int*   dst  = (const int*)d_in[1];
    const float* prev = (const float*)d_in[2];
    const float* nsrc = (const float*)d_in[3];
    const float* ndst = (const float*)d_in[4];
    const float* Wnig = (const float*)d_in[5];
    const float* bnig = (const float*)d_in[6];
    const float* Wnode = (const float*)d_in[7];
    const float* bnode = (const float*)d_in[8];
    float* out = (float*)d_out;

    const size_t OWNER_B = (size_t)NN * 4;
    const size_t PA_B = 32 * 64 * 8 * 2;
    if (ws_size < OWNER_B + 2 * PA_B + 512) return;
    char* ws = (char*)d_ws;
    int*   owner = (int*)ws;
    short* PA = (short*)(ws + OWNER_B);
    short* PQ = (short*)(ws + OWNER_B + PA_B);
    float* cvec = (float*)(ws + OWNER_B + 2 * PA_B);

    k_init_weights<<<NB_INIT + NB_WFRAG + 1, 256, 0, stream>>>(
        owner, Wnig, bnig, Wnode, bnode, PA, PQ, cvec);
    k_claim<<<NB_CLAIM, 256, 0, stream>>>(src, dst, owner);
    k_fused<<<NB_COPY + NB_MAIN, 256, 0, stream>>>(
        src, dst, prev, nsrc, ndst, owner, PA, PQ, cvec, out);
}

// Round 3
// 252.712 us; speedup vs baseline: 1.3955x; 1.3955x over previous
//
#include <hip/hip_runtime.h>
#include <hip/hip_bf16.h>

#define B_SZ 100000
#define NTOT 200000
#define NN   1000000
#define DIM  128

#define NB_INIT   3907              // ceil(1e6/256)
#define NB_WFRAG  32
#define NB_CLAIM  782               // ceil(2e5/256)

#define TILES     62500             // 1e6 nodes / 16 per wave-tile
#define GRID_MAIN 512               // persistent: 2 blocks/CU
#define BLK_MAIN  512               // 8 waves
#define WAVES_TOT (GRID_MAIN * 8)   // 4096 wave slots

typedef short bf16x8 __attribute__((ext_vector_type(8)));
typedef float f32x4  __attribute__((ext_vector_type(4)));

__device__ __forceinline__ short f2bf(float f) {
    union { float f; unsigned u; } v; v.f = f;
    unsigned u = v.u;
    u += 0x7fffu + ((u >> 16) & 1u);
    return (short)(u >> 16);
}

// ---------------- launch 1: owner init || weight packing ----------------
//  PA[k][n] = W_node[n][k] + (k==n)            (applied to prev)
//  PQ[k][n] = sum_m W_node[n][m]*W_nig[m][k]   (applied to nbr)
//  cvec[n]  = b_node[n] + sum_k b_nig[k]*W_node[n][k]
// B-frag layout (16x16x32 bf16): frag (kc,nc), lane l holds
//   col n = nc*16 + (l&15), k = kc*32 + (l>>4)*8 + i, i=0..7
__global__ __launch_bounds__(256) void k_init_weights(
        int* __restrict__ owner,
        const float* __restrict__ Wnig, const float* __restrict__ bnig,
        const float* __restrict__ Wnode, const float* __restrict__ bnode,
        short* __restrict__ PA, short* __restrict__ PQ,
        float* __restrict__ cvec) {
    int b = blockIdx.x, t = threadIdx.x;
    if (b < NB_INIT) {
        int i = b * 256 + t;
        if (i < NN) owner[i] = -1;
    } else if (b < NB_INIT + NB_WFRAG) {
        int b2 = b - NB_INIT;              // fragment index kc*8+nc
        int lane = t & 63, ig = t >> 6;    // ig 0..3 -> i = 2*ig, 2*ig+1
        int kc = b2 >> 3, nc = b2 & 7;
        int n = nc * 16 + (lane & 15);
        int kbase = kc * 32 + (lane >> 4) * 8;
        int fo = (b2 * 64 + lane) * 8;
        for (int ii = 0; ii < 2; ++ii) {
            int i = ig * 2 + ii;
            int k = kbase + i;
            float a = Wnode[n * DIM + k] + (k == n ? 1.0f : 0.0f);
            PA[fo + i] = f2bf(a);
            float q = 0.f;
            for (int m = 0; m < DIM; ++m) q += Wnode[n * DIM + m] * Wnig[m * DIM + k];
            PQ[fo + i] = f2bf(q);
        }
    } else {
        if (t < DIM) {
            float c = bnode[t];
            for (int k = 0; k < DIM; ++k) c += bnig[k] * Wnode[t * DIM + k];
            cvec[t] = c;
        }
    }
}

// ---------------- launch 2: ownership claim ----------------
// winner = max code; src [0,B), dst [B,2B): dst beats src, later beats earlier.
__global__ void k_claim(const int* __restrict__ src, const int* __restrict__ dst,
                        int* __restrict__ owner) {
    int i = blockIdx.x * 256 + threadIdx.x;
    if (i >= NTOT) return;
    int node = (i < B_SZ) ? src[i] : dst[i - B_SZ];
    atomicMax(&owner[node], i);
}

// ---------------- launch 3: node-ordered fused update+copy ----------------
// Persistent. Each wave: 16 consecutive nodes per tile, grid-stride over tiles.
// Touched rows -> MFMA update; untouched rows -> float4 copy. Streaming prev/out.
__global__ __launch_bounds__(BLK_MAIN, 4) void k_node(
        const float* __restrict__ prev,
        const float* __restrict__ nsrc, const float* __restrict__ ndst,
        const int* __restrict__ owner,
        const short* __restrict__ PA, const short* __restrict__ PQ,
        const float* __restrict__ cvec,
        float* __restrict__ out) {
    __shared__ __align__(16) short lA[32 * 64 * 8];   // 32 KB
    __shared__ __align__(16) short lQ[32 * 64 * 8];   // 32 KB
    int tid = threadIdx.x;
    {
        const float4* gA = (const float4*)PA;
        const float4* gQ = (const float4*)PQ;
        float4* sA = (float4*)lA;
        float4* sQ = (float4*)lQ;
        for (int i = tid; i < 2048; i += BLK_MAIN) { sA[i] = gA[i]; sQ[i] = gQ[i]; }
    }
    __syncthreads();

    int wave = tid >> 6, lane = tid & 63;
    int wid = blockIdx.x * 8 + wave;
    int myrow = lane & 15;
    int koff = (lane >> 4) * 8;
    int col0 = lane & 15;
    int rbase = (lane >> 4) * 4;

    // bias slice: constant per lane across tiles
    float cv[8];
#pragma unroll
    for (int nc = 0; nc < 8; ++nc) cv[nc] = cvec[nc * 16 + col0];

    for (int tile = wid; tile < TILES; tile += WAVES_TOT) {
        int nbase = tile * 16;
        int my_owner = owner[nbase + myrow];
        unsigned mask16 = (unsigned)(__ballot(my_owner >= 0) & 0xFFFFu);

        if (mask16) {
            const float* prow = prev + (size_t)(nbase + myrow) * DIM;
            const float* nrow = prow;  // dummy init
            if (my_owner >= 0) {
                bool is_src = my_owner < B_SZ;
                int bi = is_src ? my_owner : my_owner - B_SZ;
                nrow = (is_src ? nsrc : ndst) + (size_t)bi * DIM;
            }
            f32x4 acc[8];
#pragma unroll
            for (int nc = 0; nc < 8; ++nc) acc[nc] = (f32x4){0.f, 0.f, 0.f, 0.f};

#pragma unroll
            for (int kc = 0; kc < 4; ++kc) {
                int k0 = kc * 32 + koff;
                bf16x8 aP = (bf16x8){0,0,0,0,0,0,0,0};
                bf16x8 aN = (bf16x8){0,0,0,0,0,0,0,0};
                if (my_owner >= 0) {
                    float4 p0 = *(const float4*)(prow + k0);
                    float4 p1 = *(const float4*)(prow + k0 + 4);
                    float4 n0 = *(const float4*)(nrow + k0);
                    float4 n1 = *(const float4*)(nrow + k0 + 4);
                    aP[0]=f2bf(p0.x); aP[1]=f2bf(p0.y); aP[2]=f2bf(p0.z); aP[3]=f2bf(p0.w);
                    aP[4]=f2bf(p1.x); aP[5]=f2bf(p1.y); aP[6]=f2bf(p1.z); aP[7]=f2bf(p1.w);
                    aN[0]=f2bf(n0.x); aN[1]=f2bf(n0.y); aN[2]=f2bf(n0.z); aN[3]=f2bf(n0.w);
                    aN[4]=f2bf(n1.x); aN[5]=f2bf(n1.y); aN[6]=f2bf(n1.z); aN[7]=f2bf(n1.w);
                }
#pragma unroll
                for (int nc = 0; nc < 8; ++nc) {
                    int fo = ((kc * 8 + nc) * 64 + lane) * 8;
                    bf16x8 bA = *(const bf16x8*)(lA + fo);
                    bf16x8 bQ = *(const bf16x8*)(lQ + fo);
                    acc[nc] = __builtin_amdgcn_mfma_f32_16x16x32_bf16(aP, bA, acc[nc], 0, 0, 0);
                    acc[nc] = __builtin_amdgcn_mfma_f32_16x16x32_bf16(aN, bQ, acc[nc], 0, 0, 0);
                }
            }
            // epilogue: touched rows from acc (D: col = l&15, row = (l>>4)*4 + r)
#pragma unroll
            for (int r = 0; r < 4; ++r) {
                int rt = rbase + r;
                if ((mask16 >> rt) & 1u) {
                    float* orow = out + (size_t)(nbase + rt) * DIM;
#pragma unroll
                    for (int nc = 0; nc < 8; ++nc)
                        orow[nc * 16 + col0] = acc[nc][r] + cv[nc];
                }
            }
        }

        // untouched rows: coalesced copy, two rows per iteration (1 KB/instr)
        unsigned um = (~mask16) & 0xFFFFu;
        while (um) {
            int r0 = __builtin_ctz(um); um &= um - 1;
            int r1 = -1;
            if (um) { r1 = __builtin_ctz(um); um &= um - 1; }
            int r = (lane < 32) ? r0 : r1;
            if (r >= 0) {
                const float4* s4 = (const float4*)(prev + (size_t)(nbase + r) * DIM);
                float4* d4 = (float4*)(out + (size_t)(nbase + r) * DIM);
                d4[lane & 31] = s4[lane & 31];
            }
        }
    }
}

extern "C" void kernel_launch(void* const* d_in, const int* in_sizes, int n_in,
                              void* d_out, int out_size, void* d_ws, size_t ws_size,
                              hipStream_t stream) {
    const int*   src  = (const int*)d_in[0];
    const int*   dst  = (const int*)d_in[1];
    const float* prev = (const float*)d_in[2];
    const float* nsrc = (const float*)d_in[3];
    const float* ndst = (const float*)d_in[4];
    const float* Wnig = (const float*)d_in[5];
    const float* bnig = (const float*)d_in[6];
    const float* Wnode = (const float*)d_in[7];
    const float* bnode = (const float*)d_in[8];
    float* out = (float*)d_out;

    const size_t OWNER_B = (size_t)NN * 4;
    const size_t PA_B = 32 * 64 * 8 * 2;     // 32 KB each
    if (ws_size < OWNER_B + 2 * PA_B + 512) return;
    char* ws = (char*)d_ws;
    int*   owner = (int*)ws;
    short* PA = (short*)(ws + OWNER_B);
    short* PQ = (short*)(ws + OWNER_B + PA_B);
    float* cvec = (float*)(ws + OWNER_B + 2 * PA_B);

    k_init_weights<<<NB_INIT + NB_WFRAG + 1, 256, 0, stream>>>(
        owner, Wnig, bnig, Wnode, bnode, PA, PQ, cvec);
    k_claim<<<NB_CLAIM, 256, 0, stream>>>(src, dst, owner);
    k_node<<<GRID_MAIN, BLK_MAIN, 0, stream>>>(
        prev, nsrc, ndst, owner, PA, PQ, cvec, out);
}